// Round 7
// baseline (288.694 us; speedup 1.0000x reference)
//
#include <hip/hip_runtime.h>
#include <hip/hip_bf16.h>

#define Bb 256
#define Ss 2048
#define Tt 48
#define NCK 12           // chunks per batch (pws = 14.16 MB, proven size)
#define CLEN 171         // steps per chunk (last chunk: 166)

static constexpr float C_SHIFT = 4.875f;  // ~ln(48)+1: per-step growth ~= 1

typedef float f4   __attribute__((ext_vector_type(4)));
typedef short s4h  __attribute__((ext_vector_type(4)));
typedef __bf16 bf16x8 __attribute__((ext_vector_type(8)));

union U32x4 { unsigned u[4]; bf16x8 v; };
union U32x2 { unsigned u[2]; s4h v; };

__device__ __forceinline__ unsigned pk_trunc(float lo, float hi) {
    unsigned a = __builtin_bit_cast(unsigned, lo);
    unsigned b = __builtin_bit_cast(unsigned, hi);
#if __has_builtin(__builtin_amdgcn_perm)
    return __builtin_amdgcn_perm(b, a, 0x07060302u);
#else
    return (b & 0xFFFF0000u) | (a >> 16);
#endif
}
__device__ __forceinline__ unsigned pk_rne(float lo, float hi) {
    __hip_bfloat162 h = __float22bfloat162_rn(make_float2(lo, hi));
    union { __hip_bfloat16 b[2]; unsigned u; } t;
    t.b[0] = h.x; t.b[1] = h.y;
    return t.u;
}
__device__ __forceinline__ float bfu(unsigned u) { return __builtin_bit_cast(float, u); }

// k-slot bijection for the x32 operands: slot (g,j) holds k = sig(g,j).
__device__ __forceinline__ int sig32(int g, int j) {
    return 16 * (j >> 2) + 4 * g + (j & 3);
}

#define MFMA32(a,b,c) __builtin_amdgcn_mfma_f32_16x16x32_bf16(a, b, c, 0, 0, 0)
#define MFMA16(a,b,c) __builtin_amdgcn_mfma_f32_16x16x16bf16_1k(a, b, c, 0, 0, 0)

// Per-step scaled A operand set (bf16): Ae = diag(e_step) * A.
struct AE { bf16x8 a32[3]; s4h a16[3]; };

// Build Ae from the f32 A-master. Output-row of the A-fragment = 16mt + c0,
// so the scale is ONE scalar per lane per m-tile: e[16mt + c0]. Depends only
// on staged e -- fully independent of the matrix chain (overlaps MFMAs).
__device__ __forceinline__ void mkAe(const float (&A32f)[3][8], const float (&A16f)[3][4],
                                     const float* __restrict__ erow, int c0, AE& o)
{
#pragma unroll
    for (int mt = 0; mt < 3; ++mt) {
        float e = erow[16 * mt + c0];          // ds_read_b32, quad-broadcast
        U32x4 a;
        a.u[0] = pk_rne(A32f[mt][0] * e, A32f[mt][1] * e);
        a.u[1] = pk_rne(A32f[mt][2] * e, A32f[mt][3] * e);
        a.u[2] = pk_rne(A32f[mt][4] * e, A32f[mt][5] * e);
        a.u[3] = pk_rne(A32f[mt][6] * e, A32f[mt][7] * e);
        o.a32[mt] = a.v;
        U32x2 c;
        c.u[0] = pk_rne(A16f[mt][0] * e, A16f[mt][1] * e);
        c.u[1] = pk_rne(A16f[mt][2] * e, A16f[mt][3] * e);
        o.a16[mt] = c.v;
    }
}

// One scan step with pre-scaled A: B <- pack(Ae * B). Pack is pure perms --
// the serial chain is now MFMA32 -> MFMA16 -> perm -> next MFMA.
__device__ __forceinline__ void step_mm(const AE& A, bf16x8 (&B32)[3], s4h (&B16)[3])
{
    const f4 z = {0.f, 0.f, 0.f, 0.f};
#pragma unroll
    for (int nt = 0; nt < 3; ++nt) {
        f4 c0v = MFMA32(A.a32[0], B32[nt], z);
        f4 c1v = MFMA32(A.a32[1], B32[nt], z);
        f4 c2v = MFMA32(A.a32[2], B32[nt], z);
        c0v = MFMA16(A.a16[0], B16[nt], c0v);
        c1v = MFMA16(A.a16[1], B16[nt], c1v);
        c2v = MFMA16(A.a16[2], B16[nt], c2v);
        U32x4 nb;
        nb.u[0] = pk_trunc(c0v[0], c0v[1]);
        nb.u[1] = pk_trunc(c0v[2], c0v[3]);
        nb.u[2] = pk_trunc(c1v[0], c1v[1]);
        nb.u[3] = pk_trunc(c1v[2], c1v[3]);
        B32[nt] = nb.v;
        U32x2 nc;
        nc.u[0] = pk_trunc(c2v[0], c2v[1]);
        nc.u[1] = pk_trunc(c2v[2], c2v[3]);
        B16[nt] = nc.v;
    }
}

// ---------------------------------------------------------------------------
// Phase 1: one wave per (batch, chunk): 48x48 transfer-matrix product in regs.
// 768 blocks x 4 waves = 3072 waves = 256 batches x 12 chunks (3 blocks/CU).
// A-master kept in f32 registers; per step Ae = diag(e)*A built OFF-chain
// (static 2-slot pipeline, one step ahead), pack de-scaled to pure perms.
// ---------------------------------------------------------------------------
__global__ __launch_bounds__(256, 3)
void crf_scan(const float* __restrict__ em, const float* __restrict__ trn,
              float* __restrict__ pws, float* __restrict__ outz)
{
    __shared__ float lex[4][16 * Tt];          // per-wave 16-step exp(em) buffer
    const int tid = threadIdx.x, wv = tid >> 6, l = tid & 63;
    const int c0 = l & 15, g = l >> 4;
    const int wid = blockIdx.x * 4 + wv;
    const int b = wid / NCK, ck = wid % NCK;
    if (blockIdx.x == 0 && tid == 0) outz[0] = 0.0f;   // zero d_out for finish

    // A-master (f32): A32f[mt][j] = exp(trn[sig32(g,j)][16mt+c0]);
    //                 A16f[mt][j] = exp(trn[32+4g+j][16mt+c0])
    float A32f[3][8]; float A16f[3][4];
#pragma unroll
    for (int mt = 0; mt < 3; ++mt) {
#pragma unroll
        for (int j = 0; j < 8; ++j)
            A32f[mt][j] = __expf(trn[sig32(g, j) * Tt + 16 * mt + c0]);
#pragma unroll
        for (int j = 0; j < 4; ++j)
            A16f[mt][j] = __expf(trn[(32 + 4 * g + j) * Tt + 16 * mt + c0]);
    }

    // State init = identity
    bf16x8 B32[3]; s4h B16[3];
#pragma unroll
    for (int nt = 0; nt < 3; ++nt) {
        U32x4 bi;
#pragma unroll
        for (int q = 0; q < 4; ++q) {
            unsigned lo = (sig32(g, 2 * q)     == 16 * nt + c0) ? 0x3F80u : 0u;
            unsigned hi = (sig32(g, 2 * q + 1) == 16 * nt + c0) ? 0x3F80u : 0u;
            bi.u[q] = lo | (hi << 16);
        }
        B32[nt] = bi.v;
        U32x2 ci;
#pragma unroll
        for (int q = 0; q < 2; ++q) {
            unsigned lo = (nt == 2 && 4 * g + 2 * q     == c0) ? 0x3F80u : 0u;
            unsigned hi = (nt == 2 && 4 * g + 2 * q + 1 == c0) ? 0x3F80u : 0u;
            ci.u[q] = lo | (hi << 16);
        }
        B16[nt] = ci.v;
    }

    const int total = (ck == NCK - 1) ? (Ss - 1 - ck * CLEN) : CLEN;  // 171 / 166
    const int s0 = ck * CLEN + 1;
    const float* emb = em + (size_t)b * (Ss * Tt);
    float* lw = &lex[wv][0];
    const long lim = (long)Ss * Tt - 4;

    // prefetch sub 0 (early-issued global loads, consumed at loop top)
    f4 r[3];
#pragma unroll
    for (int i = 0; i < 3; ++i) {
        long o = (long)s0 * Tt + l * 4 + i * 256;
        if (o > lim) o = lim;
        r[i] = *(const f4*)(emb + o);
    }

    const int nsub = (total + 15) >> 4;
    for (int sub = 0; sub < nsub; ++sub) {
#pragma unroll
        for (int i = 0; i < 3; ++i)
#pragma unroll
            for (int j = 0; j < 4; ++j) r[i][j] = __expf(r[i][j] - C_SHIFT);
#pragma unroll
        for (int i = 0; i < 3; ++i) *(f4*)(lw + l * 4 + i * 256) = r[i];

        if (sub + 1 < nsub) {        // issue next sub's loads before compute
#pragma unroll
            for (int i = 0; i < 3; ++i) {
                long o = (long)(s0 + (sub + 1) * 16) * Tt + l * 4 + i * 256;
                if (o > lim) o = lim;
                r[i] = *(const f4*)(emb + o);
            }
        }

        int nsteps = total - sub * 16;
        if (nsteps >= 16) {
            AE ae[2];                                  // static indices under unroll
            mkAe(A32f, A16f, lw + 0 * Tt, c0, ae[0]);
#pragma unroll
            for (int u = 0; u < 16; ++u) {
                if (u + 1 < 16)                        // prep next Ae off-chain
                    mkAe(A32f, A16f, lw + (u + 1) * Tt, c0, ae[(u + 1) & 1]);
                step_mm(ae[u & 1], B32, B16);
            }
        } else {
            for (int u = 0; u < nsteps; ++u) {
                AE a1;
                mkAe(A32f, A16f, lw + u * Tt, c0, a1);
                step_mm(a1, B32, B16);
            }
        }
    }

    // store 18 u32/lane, coalesced
    unsigned* pw = (unsigned*)pws + (size_t)wid * 1152 + l;
#pragma unroll
    for (int nt = 0; nt < 3; ++nt) {
        U32x4 a; a.v = B32[nt];
        U32x2 c; c.v = B16[nt];
        pw[(nt * 6 + 0) * 64] = a.u[0];
        pw[(nt * 6 + 1) * 64] = a.u[1];
        pw[(nt * 6 + 2) * 64] = a.u[2];
        pw[(nt * 6 + 3) * 64] = a.u[3];
        pw[(nt * 6 + 4) * 64] = c.u[0];
        pw[(nt * 6 + 5) * 64] = c.u[1];
    }
}

// ---------------------------------------------------------------------------
// Phase 2 + gold, merged: one block per batch; wave 0 chains the 12 chunk
// matrices with renorm, combines with gold. (Round-0 proven version.)
// ---------------------------------------------------------------------------
__global__ __launch_bounds__(256)
void crf_finish(const float* __restrict__ em, const int* __restrict__ tags,
                const int* __restrict__ mask, const float* __restrict__ trn,
                const float* __restrict__ stt, const float* __restrict__ ent,
                const float* __restrict__ pws, float* __restrict__ out)
{
    __shared__ float red[256];
    __shared__ float alpha[Tt];
    const int b = blockIdx.x, t = threadIdx.x;

    // gold partial
    const int* tg = tags + (size_t)b * Ss;
    float local = 0.0f;
    for (int s = t; s < Ss; s += 256) {
        if (s > 0) {
            int pv = tg[s - 1], cu = tg[s];
            float mf = (float)mask[(size_t)b * Ss + s];
            local += (trn[pv * Tt + cu] + em[((size_t)b * Ss + s) * Tt + cu]) * mf;
        }
    }
    if (t == 0) {
        int t0 = tg[0];
        local += stt[t0] + em[(size_t)b * Ss * Tt + t0];
        local += ent[tg[Ss - 1]];
    }
    red[t] = local;
    __syncthreads();
    if (t < 128) red[t] += red[t + 128];
    __syncthreads();

    if (t < 64) {
        const int l = t, c0 = l & 15, g = l >> 4;
        float gsum = red[l] + red[l + 64];
#pragma unroll
        for (int m = 32; m >= 1; m >>= 1) gsum += __shfl_xor(gsum, m);

        if (l < Tt) alpha[l] = __expf(stt[l] + em[(size_t)b * Ss * Tt + l] - C_SHIFT);

        float acc = 0.0f;
        const unsigned* pw = (const unsigned*)pws + (size_t)b * NCK * 1152 + l;
        for (int ck = 0; ck < NCK; ++ck) {
            float y[12];
#pragma unroll
            for (int i = 0; i < 12; ++i) y[i] = 0.0f;
#pragma unroll
            for (int nt = 0; nt < 3; ++nt) {
                float av = alpha[16 * nt + c0];
                unsigned w[6];
#pragma unroll
                for (int q = 0; q < 6; ++q) w[q] = pw[(size_t)ck * 1152 + (nt * 6 + q) * 64];
#pragma unroll
                for (int q = 0; q < 6; ++q) {
                    y[2 * q]     += bfu(w[q] << 16)         * av;
                    y[2 * q + 1] += bfu(w[q] & 0xFFFF0000u) * av;
                }
            }
#pragma unroll
            for (int m = 1; m <= 8; m <<= 1)
#pragma unroll
                for (int i = 0; i < 12; ++i) y[i] += __shfl_xor(y[i], m);
            float mx = y[0];
#pragma unroll
            for (int i = 1; i < 12; ++i) mx = fmaxf(mx, y[i]);
            mx = fmaxf(mx, __shfl_xor(mx, 16));
            mx = fmaxf(mx, __shfl_xor(mx, 32));
            acc += __logf(mx);
            float rm = 1.0f / mx;
            if (c0 == 0) {
#pragma unroll
                for (int tt = 0; tt < 3; ++tt)
#pragma unroll
                    for (int rr = 0; rr < 4; ++rr)
                        alpha[16 * tt + 4 * g + rr] = y[4 * tt + rr] * rm;
            }
        }
        // fwd = log(sum alpha * exp(ent)) + acc + S*C
        float part = (l < Tt) ? alpha[l] * __expf(ent[l]) : 0.0f;
#pragma unroll
        for (int m = 32; m >= 1; m >>= 1) part += __shfl_xor(part, m);
        if (t == 0) {
            float fwd = __logf(part) + acc + (float)Ss * C_SHIFT;
            atomicAdd(out, (fwd - gsum) * (1.0f / 256.0f));
        }
    }
}

// ---------------------------------------------------------------------------
extern "C" void kernel_launch(void* const* d_in, const int* in_sizes, int n_in,
                              void* d_out, int out_size, void* d_ws, size_t ws_size,
                              hipStream_t stream)
{
    const float* em  = (const float*)d_in[0];
    const int* tags  = (const int*)d_in[1];
    const int* mask  = (const int*)d_in[2];
    const float* trn = (const float*)d_in[3];
    const float* stt = (const float*)d_in[4];
    const float* ent = (const float*)d_in[5];
    float* out = (float*)d_out;
    float* pws = (float*)d_ws;   // 3072 waves x 1152 u32 = 14.16 MB (proven safe)

    crf_scan<<<768, 256, 0, stream>>>(em, trn, pws, out);
    crf_finish<<<256, 256, 0, stream>>>(em, tags, mask, trn, stt, ent, pws, out);
}

// Round 8
// 244.219 us; speedup vs baseline: 1.1821x; 1.1821x over previous
//
#include <hip/hip_runtime.h>
#include <hip/hip_bf16.h>

#define Bb 256
#define Ss 2048
#define Tt 48
#define NCK 12           // chunks per batch (pws = 14.16 MB, proven size)
#define CLEN 171         // steps per chunk (last chunk: 166)

static constexpr float C_SHIFT = 4.875f;  // ~ln(48)+1: per-step growth ~= 1

typedef float f4   __attribute__((ext_vector_type(4)));
typedef short s4h  __attribute__((ext_vector_type(4)));
typedef __bf16 bf16x8 __attribute__((ext_vector_type(8)));

union U32x4 { unsigned u[4]; bf16x8 v; };
union U32x2 { unsigned u[2]; s4h v; };

__device__ __forceinline__ unsigned pk_trunc(float lo, float hi) {
    unsigned a = __builtin_bit_cast(unsigned, lo);
    unsigned b = __builtin_bit_cast(unsigned, hi);
#if __has_builtin(__builtin_amdgcn_perm)
    return __builtin_amdgcn_perm(b, a, 0x07060302u);
#else
    return (b & 0xFFFF0000u) | (a >> 16);
#endif
}
__device__ __forceinline__ unsigned pk_rne(float lo, float hi) {
    __hip_bfloat162 h = __float22bfloat162_rn(make_float2(lo, hi));
    union { __hip_bfloat16 b[2]; unsigned u; } t;
    t.b[0] = h.x; t.b[1] = h.y;
    return t.u;
}
__device__ __forceinline__ float bfu(unsigned u) { return __builtin_bit_cast(float, u); }

// k-slot bijection for the x32 operands: slot (g,j) holds k = sig(g,j).
__device__ __forceinline__ int sig32(int g, int j) {
    return 16 * (j >> 2) + 4 * g + (j & 3);
}

#define MFMA32(a,b,c) __builtin_amdgcn_mfma_f32_16x16x32_bf16(a, b, c, 0, 0, 0)
#define MFMA16(a,b,c) __builtin_amdgcn_mfma_f32_16x16x16bf16_1k(a, b, c, 0, 0, 0)

// ---------------------------------------------------------------------------
// One scan step (round-0 proven): per n-tile, D = A32*B32 (rows 0..31) +
// A16*B16 (rows 32..47), rowscale by e, repack (natural row space).
// ---------------------------------------------------------------------------
__device__ __forceinline__ void scan_step(const bf16x8 (&A32)[3], const s4h (&A16)[3],
                                          bf16x8 (&B32)[3], s4h (&B16)[3],
                                          const float* __restrict__ eb)
{
    f4 e0 = *(const f4*)(eb);          // e[4g + 0..3]      (rows of m-tile 0)
    f4 e1 = *(const f4*)(eb + 16);     // e[16 + 4g + 0..3] (m-tile 1)
    f4 e2 = *(const f4*)(eb + 32);     // e[32 + 4g + 0..3] (m-tile 2)
    const f4 z = {0.f, 0.f, 0.f, 0.f};
#pragma unroll
    for (int nt = 0; nt < 3; ++nt) {
        f4 c0v = MFMA32(A32[0], B32[nt], z);
        f4 c1v = MFMA32(A32[1], B32[nt], z);
        f4 c2v = MFMA32(A32[2], B32[nt], z);
        c0v = MFMA16(A16[0], B16[nt], c0v);
        c1v = MFMA16(A16[1], B16[nt], c1v);
        c2v = MFMA16(A16[2], B16[nt], c2v);
        U32x4 nb;
        nb.u[0] = pk_trunc(c0v[0] * e0[0], c0v[1] * e0[1]);
        nb.u[1] = pk_trunc(c0v[2] * e0[2], c0v[3] * e0[3]);
        nb.u[2] = pk_trunc(c1v[0] * e1[0], c1v[1] * e1[1]);
        nb.u[3] = pk_trunc(c1v[2] * e1[2], c1v[3] * e1[3]);
        B32[nt] = nb.v;
        U32x2 nc;
        nc.u[0] = pk_trunc(c2v[0] * e2[0], c2v[1] * e2[1]);
        nc.u[1] = pk_trunc(c2v[2] * e2[2], c2v[3] * e2[3]);
        B16[nt] = nc.v;
    }
}

// ---------------------------------------------------------------------------
// Phase 1: one wave per (batch, chunk): 48x48 transfer-matrix product in regs.
// 768 blocks x 4 waves = 3072 waves = 256 batches x 12 chunks (3 blocks/CU).
// BYTE-IDENTICAL to the round-0-proven kernel (plateau: ~114 us; 7 structural
// attacks all regressed or were neutral -- do not touch).
// ---------------------------------------------------------------------------
__global__ __launch_bounds__(256, 3)
void crf_scan(const float* __restrict__ em, const float* __restrict__ trn,
              float* __restrict__ pws, float* __restrict__ outz)
{
    __shared__ float lex[4][16 * Tt];          // per-wave 16-step exp(em) buffer
    const int tid = threadIdx.x, wv = tid >> 6, l = tid & 63;
    const int c0 = l & 15, g = l >> 4;
    const int wid = blockIdx.x * 4 + wv;
    const int b = wid / NCK, ck = wid % NCK;
    if (blockIdx.x == 0 && tid == 0) outz[0] = 0.0f;   // zero d_out for finish

    // A-frags: A32[mt] slot (g,j) = exp(trn[sig32(g,j)][16mt+c0])
    bf16x8 A32[3]; s4h A16[3];
#pragma unroll
    for (int mt = 0; mt < 3; ++mt) {
        float v[8];
#pragma unroll
        for (int j = 0; j < 8; ++j)
            v[j] = __expf(trn[sig32(g, j) * Tt + 16 * mt + c0]);
        U32x4 a;
        a.u[0] = pk_rne(v[0], v[1]); a.u[1] = pk_rne(v[2], v[3]);
        a.u[2] = pk_rne(v[4], v[5]); a.u[3] = pk_rne(v[6], v[7]);
        A32[mt] = a.v;
        float w0 = __expf(trn[(32 + 4 * g + 0) * Tt + 16 * mt + c0]);
        float w1 = __expf(trn[(32 + 4 * g + 1) * Tt + 16 * mt + c0]);
        float w2 = __expf(trn[(32 + 4 * g + 2) * Tt + 16 * mt + c0]);
        float w3 = __expf(trn[(32 + 4 * g + 3) * Tt + 16 * mt + c0]);
        U32x2 c;
        c.u[0] = pk_rne(w0, w1); c.u[1] = pk_rne(w2, w3);
        A16[mt] = c.v;
    }

    // State init = identity
    bf16x8 B32[3]; s4h B16[3];
#pragma unroll
    for (int nt = 0; nt < 3; ++nt) {
        U32x4 bi;
#pragma unroll
        for (int q = 0; q < 4; ++q) {
            unsigned lo = (sig32(g, 2 * q)     == 16 * nt + c0) ? 0x3F80u : 0u;
            unsigned hi = (sig32(g, 2 * q + 1) == 16 * nt + c0) ? 0x3F80u : 0u;
            bi.u[q] = lo | (hi << 16);
        }
        B32[nt] = bi.v;
        U32x2 ci;
#pragma unroll
        for (int q = 0; q < 2; ++q) {
            unsigned lo = (nt == 2 && 4 * g + 2 * q     == c0) ? 0x3F80u : 0u;
            unsigned hi = (nt == 2 && 4 * g + 2 * q + 1 == c0) ? 0x3F80u : 0u;
            ci.u[q] = lo | (hi << 16);
        }
        B16[nt] = ci.v;
    }

    const int total = (ck == NCK - 1) ? (Ss - 1 - ck * CLEN) : CLEN;  // 171 / 166
    const int s0 = ck * CLEN + 1;
    const float* emb = em + (size_t)b * (Ss * Tt);
    float* lw = &lex[wv][0];
    const float* lexg = lw + g * 4;
    const long lim = (long)Ss * Tt - 4;

    // prefetch sub 0 (early-issued global loads, consumed at loop top)
    f4 r[3];
#pragma unroll
    for (int i = 0; i < 3; ++i) {
        long o = (long)s0 * Tt + l * 4 + i * 256;
        if (o > lim) o = lim;
        r[i] = *(const f4*)(emb + o);
    }

    const int nsub = (total + 15) >> 4;
    for (int sub = 0; sub < nsub; ++sub) {
#pragma unroll
        for (int i = 0; i < 3; ++i)
#pragma unroll
            for (int j = 0; j < 4; ++j) r[i][j] = __expf(r[i][j] - C_SHIFT);
#pragma unroll
        for (int i = 0; i < 3; ++i) *(f4*)(lw + l * 4 + i * 256) = r[i];

        if (sub + 1 < nsub) {        // issue next sub's loads before compute
#pragma unroll
            for (int i = 0; i < 3; ++i) {
                long o = (long)(s0 + (sub + 1) * 16) * Tt + l * 4 + i * 256;
                if (o > lim) o = lim;
                r[i] = *(const f4*)(emb + o);
            }
        }

        int nsteps = total - sub * 16;
        if (nsteps >= 16) {
#pragma unroll
            for (int u = 0; u < 16; ++u)
                scan_step(A32, A16, B32, B16, lexg + u * Tt);
        } else {
            for (int u = 0; u < nsteps; ++u)
                scan_step(A32, A16, B32, B16, lexg + u * Tt);
        }
    }

    // store 18 u32/lane, coalesced
    unsigned* pw = (unsigned*)pws + (size_t)wid * 1152 + l;
#pragma unroll
    for (int nt = 0; nt < 3; ++nt) {
        U32x4 a; a.v = B32[nt];
        U32x2 c; c.v = B16[nt];
        pw[(nt * 6 + 0) * 64] = a.u[0];
        pw[(nt * 6 + 1) * 64] = a.u[1];
        pw[(nt * 6 + 2) * 64] = a.u[2];
        pw[(nt * 6 + 3) * 64] = a.u[3];
        pw[(nt * 6 + 4) * 64] = c.u[0];
        pw[(nt * 6 + 5) * 64] = c.u[1];
    }
}

// ---------------------------------------------------------------------------
// Phase 2 + gold, OVERLAPPED: one block per batch.
//   wave 0        : edge terms + alpha init + the 12-chunk renorm chain
//                   (2-deep register prefetch of pws, R1-proven pattern)
//   waves 1..3    : gold interior sum (2047 scattered gathers over 192 thr)
// The two phases ran serially in round 0 (~26 us); they are independent, so
// overlapping them costs max() not sum(). One __syncthreads, one atomicAdd.
// ---------------------------------------------------------------------------
__global__ __launch_bounds__(256)
void crf_finish(const float* __restrict__ em, const int* __restrict__ tags,
                const int* __restrict__ mask, const float* __restrict__ trn,
                const float* __restrict__ stt, const float* __restrict__ ent,
                const float* __restrict__ pws, float* __restrict__ out)
{
    __shared__ float gred[3];
    __shared__ float alpha[Tt];
    const int b = blockIdx.x, t = threadIdx.x;
    const int* tg = tags + (size_t)b * Ss;

    float result = 0.0f;     // lane t==0 carries fwd - edge across the barrier

    if (t >= 64) {
        // ---- gold interior: s in [1, 2048) over 192 threads ----
        float local = 0.0f;
        for (int s = t - 63; s < Ss; s += 192) {
            int pv = tg[s - 1], cu = tg[s];
            float mf = (float)mask[(size_t)b * Ss + s];
            local += (trn[pv * Tt + cu] + em[((size_t)b * Ss + s) * Tt + cu]) * mf;
        }
#pragma unroll
        for (int m = 32; m >= 1; m >>= 1) local += __shfl_xor(local, m);
        if ((t & 63) == 0) gred[(t >> 6) - 1] = local;
    } else {
        const int l = t, c0 = l & 15, g = l >> 4;

        // edge terms (scattered; issue before the chain)
        int t0 = tg[0], tl = tg[Ss - 1];
        float edge = stt[t0] + em[(size_t)b * Ss * Tt + t0] + ent[tl];

        // alpha init (natural): alpha[i] = exp(stt[i] + em[b,0,i] - C)
        if (l < Tt) alpha[l] = __expf(stt[l] + em[(size_t)b * Ss * Tt + l] - C_SHIFT);

        // 12-chunk chain, 2-deep register prefetch (static wA/wB buffers)
        const unsigned* pwb = (const unsigned*)pws + (size_t)b * NCK * 1152 + l;
        unsigned wA[18], wB[18];
#pragma unroll
        for (int q = 0; q < 18; ++q) wA[q] = pwb[q * 64];

        float acc = 0.0f;
#pragma unroll
        for (int ck = 0; ck < NCK; ++ck) {
            if (ck + 1 < NCK) {          // prefetch next chunk into idle buffer
                const unsigned* pn = pwb + (size_t)(ck + 1) * 1152;
                if (ck & 1) {
#pragma unroll
                    for (int q = 0; q < 18; ++q) wA[q] = pn[q * 64];
                } else {
#pragma unroll
                    for (int q = 0; q < 18; ++q) wB[q] = pn[q * 64];
                }
            }
            float y[12];
#pragma unroll
            for (int i = 0; i < 12; ++i) y[i] = 0.0f;
#pragma unroll
            for (int nt = 0; nt < 3; ++nt) {
                float av = alpha[16 * nt + c0];
#pragma unroll
                for (int q = 0; q < 6; ++q) {
                    unsigned wv = (ck & 1) ? wB[nt * 6 + q] : wA[nt * 6 + q]; // ck const
                    y[2 * q]     += bfu(wv << 16)         * av;
                    y[2 * q + 1] += bfu(wv & 0xFFFF0000u) * av;
                }
            }
#pragma unroll
            for (int m = 1; m <= 8; m <<= 1)
#pragma unroll
                for (int i = 0; i < 12; ++i) y[i] += __shfl_xor(y[i], m);
            float mx = y[0];
#pragma unroll
            for (int i = 1; i < 12; ++i) mx = fmaxf(mx, y[i]);
            mx = fmaxf(mx, __shfl_xor(mx, 16));
            mx = fmaxf(mx, __shfl_xor(mx, 32));
            acc += __logf(mx);
            float rm = 1.0f / mx;
            if (c0 == 0) {
#pragma unroll
                for (int tt = 0; tt < 3; ++tt)
#pragma unroll
                    for (int rr = 0; rr < 4; ++rr)
                        alpha[16 * tt + 4 * g + rr] = y[4 * tt + rr] * rm;
            }
        }
        // fwd = log(sum alpha * exp(ent)) + acc + S*C
        float part = (l < Tt) ? alpha[l] * __expf(ent[l]) : 0.0f;
#pragma unroll
        for (int m = 32; m >= 1; m >>= 1) part += __shfl_xor(part, m);
        if (l == 0) {
            float fwd = __logf(part) + acc + (float)Ss * C_SHIFT;
            result = fwd - edge;
        }
    }

    __syncthreads();
    if (t == 0) {
        float gsum = gred[0] + gred[1] + gred[2];
        atomicAdd(out, (result - gsum) * (1.0f / 256.0f));
    }
}

// ---------------------------------------------------------------------------
extern "C" void kernel_launch(void* const* d_in, const int* in_sizes, int n_in,
                              void* d_out, int out_size, void* d_ws, size_t ws_size,
                              hipStream_t stream)
{
    const float* em  = (const float*)d_in[0];
    const int* tags  = (const int*)d_in[1];
    const int* mask  = (const int*)d_in[2];
    const float* trn = (const float*)d_in[3];
    const float* stt = (const float*)d_in[4];
    const float* ent = (const float*)d_in[5];
    float* out = (float*)d_out;
    float* pws = (float*)d_ws;   // 3072 waves x 1152 u32 = 14.16 MB (proven safe)

    crf_scan<<<768, 256, 0, stream>>>(em, trn, pws, out);
    crf_finish<<<256, 256, 0, stream>>>(em, tags, mask, trn, stt, ent, pws, out);
}